// Round 22
// baseline (112.329 us; speedup 1.0000x reference)
//
#include <hip/hip_runtime.h>

#define DIM 64
#define HID 128

typedef __attribute__((ext_vector_type(8))) short short8;
typedef __attribute__((ext_vector_type(4))) float f32x4;
typedef _Float16 h16x8 __attribute__((ext_vector_type(8)));
typedef _Float16 h16x2 __attribute__((ext_vector_type(2)));
typedef unsigned short ushort_t;

#define MFMA(A, B, C) __builtin_amdgcn_mfma_f32_16x16x32_bf16((A), (B), (C), 0, 0, 0)
#define MFMAH(A, B, C) __builtin_amdgcn_mfma_f32_16x16x32_f16((A), (B), (C), 0, 0, 0)

__device__ __forceinline__ float sigm(float x) { return 1.f / (1.f + __expf(-x)); }
__device__ __forceinline__ float siluf(float x) { return x * sigm(x); }
__device__ __forceinline__ float silup(float x) { float s = sigm(x); return s + x * s * (1.f - s); }
__device__ __forceinline__ float softplusf(float x) {
    if (x > 20.f) return x;
    return log1pf(__expf(x));
}
__device__ __forceinline__ ushort_t f2bf(float f) {
    union { float f; unsigned int u; } v; v.f = f;
    unsigned int r = v.u + 0x7fffu + ((v.u >> 16) & 1u);
    return (ushort_t)(r >> 16);
}
__device__ __forceinline__ ushort_t f2h(float f) {
    _Float16 h = (_Float16)f;
    union { _Float16 h; ushort_t u; } v; v.h = h; return v.u;
}
__device__ __forceinline__ _Float16 u2h(ushort_t u) {
    union { ushort_t u; _Float16 h; } v; v.u = u; return v.h;
}

// SWF offsets (ushort elems) -- bf16, used by k1 + k2's L1
#define OFF_HW1F  0
#define OFF_HW2F  8192
#define OFF_HW2TF 24576
#define OFF_HW1TF 40960
#define OFF_DW1F  49152
#define OFF_DW2F  57344
#define OFF_DW2TF 73728
#define OFF_DW1TF 90112
#define OFF_UW1F  98304
#define OFF_UW2F  106496
#define OFF_JW1F  114688
#define OFF_BW1F  122880

// ================= prep: frag-layout weight matrices =================
// Heavy weights (fp16): elem o = kt*2048 + g*512 + n*8 + e ; k = kt*32 + g*8 + e
extern "C" __global__ __launch_bounds__(256)
void prep3_kernel(const float* __restrict__ Jw2, const float* __restrict__ Jb2,
                  const float* __restrict__ Bw2, const float* __restrict__ Bb2,
                  const float* __restrict__ Hw1, const float* __restrict__ Hw2,
                  const float* __restrict__ Dw1, const float* __restrict__ Dw2,
                  const float* __restrict__ uw1, const float* __restrict__ uw2,
                  const float* __restrict__ Jw1, const float* __restrict__ Bw1,
                  ushort_t* __restrict__ JW, ushort_t* __restrict__ BW1, ushort_t* __restrict__ BW2,
                  ushort_t* __restrict__ JbdF, ushort_t* __restrict__ Bb2F, ushort_t* __restrict__ Bb2TF,
                  ushort_t* __restrict__ SWF)
{
    const int b = blockIdx.x;
    if (b < 6144) {
        const int m = b >> 11;                       // 0:JW 1:BW1 2:BW2
        const int o = ((b & 2047) << 8) | threadIdx.x;
        const int e = o & 7, n = (o >> 3) & 63, g = (o >> 9) & 3, kt = o >> 11;
        const int k = (kt << 5) | (g << 3) | e;
        const int oi = k >> 7, h = k & 127;
        float val;
        if (m == 0)      val = Jw2[h * 4096 + n * 64 + oi] - Jw2[h * 4096 + oi * 64 + n];
        else if (m == 1) val = Bw2[h * 4096 + oi * 64 + n];
        else             val = Bw2[h * 4096 + n * 64 + oi];
        ushort_t* dst = (m == 0) ? JW : (m == 1) ? BW1 : BW2;
        dst[o] = f2h(val);
    } else if (b == 6144) {
        for (int e0 = threadIdx.x; e0 < 12288; e0 += 256) {
            const int m = e0 >> 12, o = e0 & 4095;
            const int e = o & 7, n = (o >> 3) & 63, g = (o >> 9) & 3, kb = o >> 11;
            const int k = (kb << 5) | (g << 3) | e;
            float val; ushort_t* dst;
            if (m == 0)      { val = Jb2[n * 64 + k] - Jb2[k * 64 + n]; dst = JbdF; }
            else if (m == 1) { val = Bb2[k * 64 + n];                   dst = Bb2F; }
            else             { val = Bb2[n * 64 + k];                   dst = Bb2TF; }
            dst[o] = f2h(val);
        }
    } else {
        const int e = (b - 6145) * 256 + threadIdx.x;    // 0..131071
        float val = 0.f;
        if (e < 98304) {
            const int net = e / 49152;
            const int o = e - net * 49152;
            const float* W1s = net ? Dw1 : Hw1;
            const float* W2s = net ? Dw2 : Hw2;
            if (o < 8192) {                 // W1f
                int ks = o & 31, n = (o >> 5) & 127, kt = o >> 12;
                val = W1s[(kt * 32 + ks) * 128 + n];
            } else if (o < 24576) {         // W2f
                int o2 = o - 8192;
                int ks = o2 & 31, n = (o2 >> 5) & 127, kt = o2 >> 12;
                val = W2s[(kt * 32 + ks) * 128 + n];
            } else if (o < 40960) {         // W2Tf
                int o3 = o - 24576;
                int ks = o3 & 31, n = (o3 >> 5) & 127, kt = o3 >> 12;
                val = W2s[n * 128 + kt * 32 + ks];
            } else {                        // W1Tf
                int o4 = o - 40960;
                int ks = o4 & 31, n = (o4 >> 5) & 63, kt = o4 >> 11;
                val = W1s[n * 128 + kt * 32 + ks];
            }
        } else if (e < 106496) {            // UW1f
            int o = e - 98304;
            int ks = o & 31, n = (o >> 5) & 127, kt = o >> 12;
            val = uw1[(kt * 32 + ks) * 128 + n];
        } else if (e < 114688) {            // UW2f
            int o = e - 106496;
            int ks = o & 31, n = (o >> 5) & 63, kt = o >> 11;
            val = uw2[(kt * 32 + ks) * 64 + n];
        } else if (e < 122880) {            // JW1f
            int o = e - 114688;
            int ks = o & 31, n = (o >> 5) & 127, kt = o >> 12;
            val = Jw1[(kt * 32 + ks) * 128 + n];
        } else {                            // BW1f
            int o = e - 122880;
            int ks = o & 31, n = (o >> 5) & 127, kt = o >> 12;
            val = Bw1[(kt * 32 + ks) * 128 + n];
        }
        SWF[e] = f2bf(val);
    }
}

// ================= K1: scalar nets + u-net via MFMA (32 rows/block, proven) =================
__device__ __forceinline__ void scalar_net(
    int tid, int r0,
    const ushort_t* zbp, ushort_t* S1, ushort_t* S2, ushort_t* S3,
    float* yacc, float* srow, float* Hrow,
    const ushort_t* W1f, const ushort_t* W2f, const ushort_t* W2Tf, const ushort_t* W1Tf,
    const float* B1, const float* B2, const float* W3, const float* B3,
    ushort_t* gOut, int storeH)
{
    const int lane = tid & 63, w = tid >> 6;
    const int mt = w & 1, nh = w >> 1;         // 2 row tiles x 4 col quarters
    const int cl = lane & 15, qq = lane >> 4;
    const int arow = mt * 16 + cl;
    const int crow = mt * 16 + qq * 4;

    // ---- L1 ----
    {
        short8 a0 = *(const short8*)&zbp[arow * 72 + (qq << 3)];
        short8 a1 = *(const short8*)&zbp[arow * 72 + 32 + (qq << 3)];
        #pragma unroll
        for (int nt = 0; nt < 2; ++nt) {
            int n = nh * 32 + nt * 16 + cl;
            f32x4 acc = {0.f, 0.f, 0.f, 0.f};
            short8 b0 = *(const short8*)&W1f[(n << 5) + (qq << 3)];
            short8 b1 = *(const short8*)&W1f[((128 + n) << 5) + (qq << 3)];
            acc = MFMA(a0, b0, acc); acc = MFMA(a1, b1, acc);
            float bv = B1[n];
            #pragma unroll
            for (int q = 0; q < 4; ++q) {
                float aa = acc[q] + bv;
                S1[(crow + q) * 136 + n] = f2bf(siluf(aa));
                S2[(crow + q) * 136 + n] = f2bf(silup(aa));
            }
        }
    }
    __syncthreads();
    // ---- L2 + y partial ----
    {
        short8 a[4];
        #pragma unroll
        for (int kt = 0; kt < 4; ++kt)
            a[kt] = *(const short8*)&S1[arow * 136 + kt * 32 + (qq << 3)];
        float yp[4] = {0.f, 0.f, 0.f, 0.f};
        #pragma unroll
        for (int nt = 0; nt < 2; ++nt) {
            int n = nh * 32 + nt * 16 + cl;
            f32x4 acc = {0.f, 0.f, 0.f, 0.f};
            #pragma unroll
            for (int kt = 0; kt < 4; ++kt) {
                short8 bb = *(const short8*)&W2f[((kt * 128 + n) << 5) + (qq << 3)];
                acc = MFMA(a[kt], bb, acc);
            }
            float bv = B2[n], w3v = W3[n];
            #pragma unroll
            for (int q = 0; q < 4; ++q) {
                float a2 = acc[q] + bv;
                yp[q] += siluf(a2) * w3v;
                S3[(crow + q) * 136 + n] = f2bf(w3v * silup(a2));
            }
        }
        #pragma unroll
        for (int q = 0; q < 4; ++q) {
            float p = yp[q];
            p += __shfl_xor(p, 1); p += __shfl_xor(p, 2);
            p += __shfl_xor(p, 4); p += __shfl_xor(p, 8);
            if (cl == 0) atomicAdd(&yacc[crow + q], p);
        }
    }
    __syncthreads();
    if (tid < 32) {
        float a3 = yacc[tid] + B3[0];
        srow[tid] = sigm(a3);
        if (storeH) Hrow[tid] = softplusf(a3);
        yacc[tid] = 0.f;
    }
    __syncthreads();
    // ---- bwd1 ----
    {
        short8 a[4];
        #pragma unroll
        for (int kt = 0; kt < 4; ++kt)
            a[kt] = *(const short8*)&S3[arow * 136 + kt * 32 + (qq << 3)];
        #pragma unroll
        for (int nt = 0; nt < 2; ++nt) {
            int n = nh * 32 + nt * 16 + cl;
            f32x4 acc = {0.f, 0.f, 0.f, 0.f};
            #pragma unroll
            for (int kt = 0; kt < 4; ++kt) {
                short8 bb = *(const short8*)&W2Tf[((kt * 128 + n) << 5) + (qq << 3)];
                acc = MFMA(a[kt], bb, acc);
            }
            #pragma unroll
            for (int q = 0; q < 4; ++q) {
                float sp;
                { union { unsigned int u; float f; } v;
                  v.u = ((unsigned int)S2[(crow + q) * 136 + n]) << 16; sp = v.f; }
                S1[(crow + q) * 136 + n] = f2bf(acc[q] * sp);
            }
        }
    }
    __syncthreads();
    // ---- bwd2: g -> global fp16 ----
    {
        short8 a[4];
        #pragma unroll
        for (int kt = 0; kt < 4; ++kt)
            a[kt] = *(const short8*)&S1[arow * 136 + kt * 32 + (qq << 3)];
        int n = nh * 16 + cl;
        f32x4 acc = {0.f, 0.f, 0.f, 0.f};
        #pragma unroll
        for (int kt = 0; kt < 4; ++kt) {
            short8 bb = *(const short8*)&W1Tf[((kt * 64 + n) << 5) + (qq << 3)];
            acc = MFMA(a[kt], bb, acc);
        }
        #pragma unroll
        for (int q = 0; q < 4; ++q) {
            int row = crow + q;
            gOut[(size_t)(r0 + row) * 64 + n] = f2h(srow[row] * acc[q]);
        }
    }
    __syncthreads();
}

extern "C" __global__ __launch_bounds__(512, 4)
void k1_kernel(const float* __restrict__ z,
               const float* __restrict__ Hb1, const float* __restrict__ Hb2,
               const float* __restrict__ Hw3, const float* __restrict__ Hb3,
               const float* __restrict__ Db1, const float* __restrict__ Db2,
               const float* __restrict__ Dw3, const float* __restrict__ Db3,
               const float* __restrict__ ub1, const float* __restrict__ ub2,
               const float* __restrict__ dtl, const float* __restrict__ etg,
               const ushort_t* __restrict__ SWF,
               ushort_t* __restrict__ gHbf, ushort_t* __restrict__ gDbf,
               float* __restrict__ out)
{
    __shared__ __align__(16) ushort_t zb[32][72];
    __shared__ __align__(16) ushort_t S1[32][136];
    __shared__ __align__(16) ushort_t S2[32][136];
    __shared__ __align__(16) ushort_t S3[32][136];
    __shared__ float yacc[32];
    __shared__ float srow[32];
    __shared__ float Hrow[32];

    const int tid = threadIdx.x;
    const int r0 = blockIdx.x * 32;

    {
        const float4* zg = (const float4*)(z + (size_t)r0 * 64);
        float4 v = zg[tid];
        int row = tid >> 4, c4 = (tid & 15) * 4;
        zb[row][c4 + 0] = f2bf(v.x); zb[row][c4 + 1] = f2bf(v.y);
        zb[row][c4 + 2] = f2bf(v.z); zb[row][c4 + 3] = f2bf(v.w);
        if (tid < 32) yacc[tid] = 0.f;
    }
    __syncthreads();

    scalar_net(tid, r0, &zb[0][0], &S1[0][0], &S2[0][0], &S3[0][0], yacc, srow, Hrow,
               SWF + OFF_HW1F, SWF + OFF_HW2F, SWF + OFF_HW2TF, SWF + OFF_HW1TF,
               Hb1, Hb2, Hw3, Hb3, gHbf, 1);
    scalar_net(tid, r0, &zb[0][0], &S1[0][0], &S2[0][0], &S3[0][0], yacc, srow, Hrow,
               SWF + OFF_DW1F, SWF + OFF_DW2F, SWF + OFF_DW2TF, SWF + OFF_DW1TF,
               Db1, Db2, Dw3, Db3, gDbf, 0);

    const int lane = tid & 63, w = tid >> 6;
    const int mt = w & 1, nh = w >> 1;
    const int cl = lane & 15, qq = lane >> 4;
    const int arow = mt * 16 + cl;
    const int crow = mt * 16 + qq * 4;

    // ---- u L1 (tanh) -> S1 ----
    {
        short8 a0 = *(const short8*)&zb[arow][(qq << 3)];
        short8 a1 = *(const short8*)&zb[arow][32 + (qq << 3)];
        const ushort_t* W1f = SWF + OFF_UW1F;
        #pragma unroll
        for (int nt = 0; nt < 2; ++nt) {
            int n = nh * 32 + nt * 16 + cl;
            f32x4 acc = {0.f, 0.f, 0.f, 0.f};
            short8 b0 = *(const short8*)&W1f[(n << 5) + (qq << 3)];
            short8 b1 = *(const short8*)&W1f[((128 + n) << 5) + (qq << 3)];
            acc = MFMA(a0, b0, acc); acc = MFMA(a1, b1, acc);
            float bv = ub1[n];
            #pragma unroll
            for (int q = 0; q < 4; ++q)
                S1[crow + q][n] = f2bf(tanhf(acc[q] + bv));
        }
    }
    __syncthreads();
    // ---- u L2 + base write ----
    {
        short8 a[4];
        #pragma unroll
        for (int kt = 0; kt < 4; ++kt)
            a[kt] = *(const short8*)&S1[arow][kt * 32 + (qq << 3)];
        const ushort_t* W2f = SWF + OFF_UW2F;
        const float dtv = 0.1f * sigm(dtl[0]);
        const float et = etg[0];
        int n = nh * 16 + cl;
        f32x4 acc = {0.f, 0.f, 0.f, 0.f};
        #pragma unroll
        for (int kt = 0; kt < 4; ++kt) {
            short8 bb = *(const short8*)&W2f[((kt * 64 + n) << 5) + (qq << 3)];
            acc = MFMA(a[kt], bb, acc);
        }
        float bv = ub2[n];
        #pragma unroll
        for (int q = 0; q < 4; ++q) {
            int row = crow + q;
            size_t idx = (size_t)(r0 + row) * 64 + n;
            out[idx] = z[idx] + dtv * 0.1f * (et - Hrow[row]) * (acc[q] + bv);
        }
    }
}

// ================= K2: heavy contractions, fp16, L2-direct (no weight staging) =================
// 32 rows/block, 256 threads = 4 waves: ch = col-half, ks = j parity; dual-row per wave.
#define LOADHF2H(SRC, HA, HB)                                                     \
    do {                                                                          \
        _Pragma("unroll")                                                         \
        for (int q4 = 0; q4 < 4; ++q4) {                                          \
            short8 sa = *(const short8*)&(SRC)[rr0][q4 * 32 + (qq << 3)];         \
            short8 sb = *(const short8*)&(SRC)[rr1][q4 * 32 + (qq << 3)];         \
            _Pragma("unroll")                                                     \
            for (int e = 0; e < 4; ++e) {                                         \
                h16x2 ta, tb;                                                     \
                ta[0] = u2h((ushort_t)sa[e * 2]); ta[1] = u2h((ushort_t)sa[e * 2 + 1]); \
                tb[0] = u2h((ushort_t)sb[e * 2]); tb[1] = u2h((ushort_t)sb[e * 2 + 1]); \
                (HA)[q4 * 4 + e] = ta;                                            \
                (HB)[q4 * 4 + e] = tb;                                            \
            }                                                                     \
        }                                                                         \
    } while (0)

// L2-direct heavy pass: per wave, 32 j's (parity ks), 8 b-loads + 16 MFMA per j, no barriers.
// unroll 4: ~32 loads in flight per wave to cover L2 latency.
#define HEAVY_PASS(Wbase, BFbase, G, HA, HB, A00, A01, A10, A11)                  \
    do {                                                                          \
        _Pragma("unroll 4")                                                       \
        for (int jj = 0; jj < 32; ++jj) {                                         \
            const int j = 2 * jj + ks;                                            \
            const ushort_t* bp = (Wbase) + (size_t)j * 8192 + (qq << 9);          \
            h16x8 bf0[4], bf1[4];                                                 \
            _Pragma("unroll")                                                     \
            for (int ki = 0; ki < 4; ++ki) {                                      \
                bf0[ki] = *(const h16x8*)&bp[ki * 2048 + col0 * 8];               \
                bf1[ki] = *(const h16x8*)&bp[ki * 2048 + col1 * 8];               \
            }                                                                     \
            _Float16 gA = u2h((G)[rr0][j]);                                       \
            _Float16 gB = u2h((G)[rr1][j]);                                       \
            h16x2 gA2; gA2[0] = gA; gA2[1] = gA;                                  \
            h16x2 gB2; gB2[0] = gB; gB2[1] = gB;                                  \
            _Pragma("unroll")                                                     \
            for (int ki = 0; ki < 4; ++ki) {                                      \
                union { h16x2 h2[4]; h16x8 v; } aA, aB;                           \
                _Pragma("unroll")                                                 \
                for (int e = 0; e < 4; ++e) {                                     \
                    aA.h2[e] = (HA)[ki * 4 + e] * gA2;                            \
                    aB.h2[e] = (HB)[ki * 4 + e] * gB2;                            \
                }                                                                 \
                A00 = MFMAH(aA.v, bf0[ki], A00); A01 = MFMAH(aA.v, bf1[ki], A01); \
                A10 = MFMAH(aB.v, bf0[ki], A10); A11 = MFMAH(aB.v, bf1[ki], A11); \
            }                                                                     \
        }                                                                         \
        /* bias: kb = ks, each applied exactly once per ch */                     \
        {                                                                         \
            h16x8 abA = *(const h16x8*)&(G)[rr0][(ks << 5) + (qq << 3)];          \
            h16x8 abB = *(const h16x8*)&(G)[rr1][(ks << 5) + (qq << 3)];          \
            const ushort_t* bpb = (BFbase) + (ks << 11) + (qq << 9);              \
            h16x8 b0 = *(const h16x8*)&bpb[col0 * 8];                             \
            h16x8 b1 = *(const h16x8*)&bpb[col1 * 8];                             \
            A00 = MFMAH(abA, b0, A00); A01 = MFMAH(abA, b1, A01);                 \
            A10 = MFMAH(abB, b0, A10); A11 = MFMAH(abB, b1, A11);                 \
        }                                                                         \
        /* combine ks=1 partials into ks=0 */                                     \
        __syncthreads();                                                          \
        if (ks == 1) {                                                            \
            _Pragma("unroll")                                                     \
            for (int q = 0; q < 4; ++q) {                                         \
                Pb[orow0 + q][col0] = A00[q]; Pb[orow0 + q][col1] = A01[q];       \
                Pb[orow1 + q][col0] = A10[q]; Pb[orow1 + q][col1] = A11[q];       \
            }                                                                     \
        }                                                                         \
        __syncthreads();                                                          \
        if (ks == 0) {                                                            \
            _Pragma("unroll")                                                     \
            for (int q = 0; q < 4; ++q) {                                         \
                A00[q] += Pb[orow0 + q][col0]; A01[q] += Pb[orow0 + q][col1];     \
                A10[q] += Pb[orow1 + q][col0]; A11[q] += Pb[orow1 + q][col1];     \
            }                                                                     \
        }                                                                         \
        __syncthreads();                                                          \
    } while (0)

extern "C" __global__ __launch_bounds__(256, 3)
void k2_kernel(const float* __restrict__ z,
               const float* __restrict__ Jb1, const float* __restrict__ Bb1,
               const float* __restrict__ dtl,
               const ushort_t* __restrict__ JW, const ushort_t* __restrict__ BW1,
               const ushort_t* __restrict__ BW2,
               const ushort_t* __restrict__ JbdF, const ushort_t* __restrict__ Bb2F,
               const ushort_t* __restrict__ Bb2TF,
               const ushort_t* __restrict__ SWF,
               const ushort_t* __restrict__ gHbf, const ushort_t* __restrict__ gDbf,
               float* __restrict__ out)
{
    __shared__ __align__(16) ushort_t zb[32][72];
    __shared__ __align__(16) ushort_t hJ2[32][136];   // fp16
    __shared__ __align__(16) ushort_t hB2[32][136];   // fp16
    __shared__ __align__(16) ushort_t gHb[32][72];    // fp16
    __shared__ __align__(16) ushort_t gDb[32][72];    // fp16
    __shared__ __align__(16) ushort_t vb2[32][72];    // fp16
    __shared__ __align__(16) float Pb[32][68];        // f32 partial combine

    const int tid = threadIdx.x;
    const int r0 = blockIdx.x * 32;

    // stage z (bf16), gH, gD (fp16)
    {
        const float4* zg = (const float4*)(z + (size_t)r0 * 64);
        #pragma unroll
        for (int it = 0; it < 2; ++it) {
            int i = it * 256 + tid;
            float4 v = zg[i];
            int row = i >> 4, c4 = (i & 15) * 4;
            zb[row][c4 + 0] = f2bf(v.x); zb[row][c4 + 1] = f2bf(v.y);
            zb[row][c4 + 2] = f2bf(v.z); zb[row][c4 + 3] = f2bf(v.w);
        }
        const short8* gh = (const short8*)(gHbf + (size_t)r0 * 64);
        const short8* gd = (const short8*)(gDbf + (size_t)r0 * 64);
        int row = tid >> 3, s = tid & 7;
        *(short8*)&gHb[row][s * 8] = gh[tid];
        *(short8*)&gDb[row][s * 8] = gd[tid];
    }
    __syncthreads();

    const int lane = tid & 63, w = tid >> 6;   // w in 0..3
    const int cl = lane & 15, qq = lane >> 4;
    const int mt = w & 1, nh = w >> 1;         // L1 mapping: 2 row-tiles x 2 col-halves
    const int arow = mt * 16 + cl;
    const int crowL = mt * 16 + qq * 4;

    // ---- J/B layer-1 via bf16 MFMA, outputs fp16 ----
    {
        short8 a0 = *(const short8*)&zb[arow][(qq << 3)];
        short8 a1 = *(const short8*)&zb[arow][32 + (qq << 3)];
        const ushort_t* JW1f = SWF + OFF_JW1F;
        const ushort_t* BW1f = SWF + OFF_BW1F;
        #pragma unroll
        for (int nt = 0; nt < 4; ++nt) {
            int n = nh * 64 + nt * 16 + cl;
            f32x4 accJ = {0.f, 0.f, 0.f, 0.f}, accB = {0.f, 0.f, 0.f, 0.f};
            short8 jb0 = *(const short8*)&JW1f[(n << 5) + (qq << 3)];
            short8 jb1 = *(const short8*)&JW1f[((128 + n) << 5) + (qq << 3)];
            accJ = MFMA(a0, jb0, accJ); accJ = MFMA(a1, jb1, accJ);
            short8 bb0 = *(const short8*)&BW1f[(n << 5) + (qq << 3)];
            short8 bb1 = *(const short8*)&BW1f[((128 + n) << 5) + (qq << 3)];
            accB = MFMA(a0, bb0, accB); accB = MFMA(a1, bb1, accB);
            float jbv = Jb1[n], bbv = Bb1[n];
            #pragma unroll
            for (int q = 0; q < 4; ++q) {
                hJ2[crowL + q][n] = f2h(siluf(accJ[q] + jbv));
                hB2[crowL + q][n] = f2h(siluf(accB[q] + bbv));
            }
        }
    }
    __syncthreads();

    // heavy mapping: 2 col-halves x 2 j-parities; both row-tiles per wave
    const int ch = w & 1;               // col half
    const int ks = w >> 1;              // j parity
    const int rr0 = cl;
    const int rr1 = cl + 16;
    const int col0 = ch * 32 + cl;
    const int col1 = col0 + 16;
    const int orow0 = qq * 4;
    const int orow1 = orow0 + 16;

    h16x2 hfJA[16], hfJB[16], hfBA[16], hfBB[16];
    f32x4 c00 = {0,0,0,0}, c01 = {0,0,0,0}, c10 = {0,0,0,0}, c11 = {0,0,0,0};
    f32x4 v00 = {0,0,0,0}, v01 = {0,0,0,0}, v10 = {0,0,0,0}, v11 = {0,0,0,0};
    f32x4 d00 = {0,0,0,0}, d01 = {0,0,0,0}, d10 = {0,0,0,0}, d11 = {0,0,0,0};

    // ---- pass 1: cons = (A - A^T) gH ----
    LOADHF2H(hJ2, hfJA, hfJB);
    HEAVY_PASS(JW, JbdF, gHb, hfJA, hfJB, c00, c01, c10, c11);

    // ---- pass 2: v = Bm^T gD ----
    LOADHF2H(hB2, hfBA, hfBB);
    HEAVY_PASS(BW1, Bb2F, gDb, hfBA, hfBB, v00, v01, v10, v11);

    // ks=0 holds full v -> write vb2 (fp16)
    if (ks == 0) {
        #pragma unroll
        for (int q = 0; q < 4; ++q) {
            vb2[orow0 + q][col0] = f2h(v00[q]); vb2[orow0 + q][col1] = f2h(v01[q]);
            vb2[orow1 + q][col0] = f2h(v10[q]); vb2[orow1 + q][col1] = f2h(v11[q]);
        }
    }
    __syncthreads();

    // ---- pass 3: diss = Bm v ----
    HEAVY_PASS(BW2, Bb2TF, vb2, hfBA, hfBB, d00, d01, d10, d11);

    // ---- epilogue (ks=0 holds full sums) ----
    if (ks == 0) {
        const float dtv = 0.1f * sigm(dtl[0]);
        #pragma unroll
        for (int q = 0; q < 4; ++q) {
            size_t i00 = (size_t)(r0 + orow0 + q) * 64 + col0;
            size_t i01 = (size_t)(r0 + orow0 + q) * 64 + col1;
            size_t i10 = (size_t)(r0 + orow1 + q) * 64 + col0;
            size_t i11 = (size_t)(r0 + orow1 + q) * 64 + col1;
            out[i00] += dtv * (c00[q] - d00[q]);
            out[i01] += dtv * (c01[q] - d01[q]);
            out[i10] += dtv * (c10[q] - d10[q]);
            out[i11] += dtv * (c11[q] - d11[q]);
        }
    }
}

extern "C" void kernel_launch(void* const* d_in, const int* in_sizes, int n_in,
                              void* d_out, int out_size, void* d_ws, size_t ws_size,
                              hipStream_t stream) {
    const float* p[27];
    for (int i = 0; i < 27; ++i) p[i] = (const float*)d_in[i];
    ushort_t* JW    = (ushort_t*)d_ws;
    ushort_t* BW1   = JW + 524288;
    ushort_t* BW2   = BW1 + 524288;
    ushort_t* JbdF  = BW2 + 524288;
    ushort_t* Bb2F  = JbdF + 4096;
    ushort_t* Bb2TF = Bb2F + 4096;
    ushort_t* gHbf  = Bb2TF + 4096;
    ushort_t* gDbf  = gHbf + (size_t)16384 * 64;
    ushort_t* SWF   = gDbf + (size_t)16384 * 64;

    hipLaunchKernelGGL(prep3_kernel, dim3(6657), dim3(256), 0, stream,
                       p[15], p[16], p[19], p[20],
                       p[1], p[3], p[7], p[9],
                       p[21], p[23], p[13], p[17],
                       JW, BW1, BW2, JbdF, Bb2F, Bb2TF, SWF);

    const int batch = in_sizes[0] / DIM;
    hipLaunchKernelGGL(k1_kernel, dim3(batch / 32), dim3(512), 0, stream,
                       p[0],
                       p[2], p[4], p[5], p[6],
                       p[8], p[10], p[11], p[12],
                       p[22], p[24],
                       p[25], p[26],
                       SWF, gHbf, gDbf, (float*)d_out);

    hipLaunchKernelGGL(k2_kernel, dim3(batch / 32), dim3(256), 0, stream,
                       p[0], p[14], p[18], p[25],
                       JW, BW1, BW2, JbdF, Bb2F, Bb2TF, SWF,
                       gHbf, gDbf, (float*)d_out);
}

// Round 23
// 109.902 us; speedup vs baseline: 1.0221x; 1.0221x over previous
//
#include <hip/hip_runtime.h>

#define DIM 64
#define HID 128

typedef __attribute__((ext_vector_type(8))) short short8;
typedef __attribute__((ext_vector_type(4))) float f32x4;
typedef _Float16 h16x8 __attribute__((ext_vector_type(8)));
typedef _Float16 h16x2 __attribute__((ext_vector_type(2)));
typedef unsigned short ushort_t;

#define MFMA(A, B, C) __builtin_amdgcn_mfma_f32_16x16x32_bf16((A), (B), (C), 0, 0, 0)
#define MFMAH(A, B, C) __builtin_amdgcn_mfma_f32_16x16x32_f16((A), (B), (C), 0, 0, 0)

__device__ __forceinline__ float sigm(float x) { return 1.f / (1.f + __expf(-x)); }
__device__ __forceinline__ float siluf(float x) { return x * sigm(x); }
__device__ __forceinline__ float silup(float x) { float s = sigm(x); return s + x * s * (1.f - s); }
__device__ __forceinline__ float softplusf(float x) {
    if (x > 20.f) return x;
    return log1pf(__expf(x));
}
__device__ __forceinline__ ushort_t f2bf(float f) {
    union { float f; unsigned int u; } v; v.f = f;
    unsigned int r = v.u + 0x7fffu + ((v.u >> 16) & 1u);
    return (ushort_t)(r >> 16);
}
__device__ __forceinline__ ushort_t f2h(float f) {
    _Float16 h = (_Float16)f;
    union { _Float16 h; ushort_t u; } v; v.h = h; return v.u;
}
__device__ __forceinline__ _Float16 u2h(ushort_t u) {
    union { ushort_t u; _Float16 h; } v; v.u = u; return v.h;
}

// SWF offsets (ushort elems) -- bf16, used by k1 + k2's L1
#define OFF_HW1F  0
#define OFF_HW2F  8192
#define OFF_HW2TF 24576
#define OFF_HW1TF 40960
#define OFF_DW1F  49152
#define OFF_DW2F  57344
#define OFF_DW2TF 73728
#define OFF_DW1TF 90112
#define OFF_UW1F  98304
#define OFF_UW2F  106496
#define OFF_JW1F  114688
#define OFF_BW1F  122880

// ================= prep: frag-layout weight matrices =================
// Heavy weights (fp16): elem o = kt*2048 + g*512 + n*8 + e ; k = kt*32 + g*8 + e
extern "C" __global__ __launch_bounds__(256)
void prep3_kernel(const float* __restrict__ Jw2, const float* __restrict__ Jb2,
                  const float* __restrict__ Bw2, const float* __restrict__ Bb2,
                  const float* __restrict__ Hw1, const float* __restrict__ Hw2,
                  const float* __restrict__ Dw1, const float* __restrict__ Dw2,
                  const float* __restrict__ uw1, const float* __restrict__ uw2,
                  const float* __restrict__ Jw1, const float* __restrict__ Bw1,
                  ushort_t* __restrict__ JW, ushort_t* __restrict__ BW1, ushort_t* __restrict__ BW2,
                  ushort_t* __restrict__ JbdF, ushort_t* __restrict__ Bb2F, ushort_t* __restrict__ Bb2TF,
                  ushort_t* __restrict__ SWF)
{
    const int b = blockIdx.x;
    if (b < 6144) {
        const int m = b >> 11;                       // 0:JW 1:BW1 2:BW2
        const int o = ((b & 2047) << 8) | threadIdx.x;
        const int e = o & 7, n = (o >> 3) & 63, g = (o >> 9) & 3, kt = o >> 11;
        const int k = (kt << 5) | (g << 3) | e;
        const int oi = k >> 7, h = k & 127;
        float val;
        if (m == 0)      val = Jw2[h * 4096 + n * 64 + oi] - Jw2[h * 4096 + oi * 64 + n];
        else if (m == 1) val = Bw2[h * 4096 + oi * 64 + n];
        else             val = Bw2[h * 4096 + n * 64 + oi];
        ushort_t* dst = (m == 0) ? JW : (m == 1) ? BW1 : BW2;
        dst[o] = f2h(val);
    } else if (b == 6144) {
        for (int e0 = threadIdx.x; e0 < 12288; e0 += 256) {
            const int m = e0 >> 12, o = e0 & 4095;
            const int e = o & 7, n = (o >> 3) & 63, g = (o >> 9) & 3, kb = o >> 11;
            const int k = (kb << 5) | (g << 3) | e;
            float val; ushort_t* dst;
            if (m == 0)      { val = Jb2[n * 64 + k] - Jb2[k * 64 + n]; dst = JbdF; }
            else if (m == 1) { val = Bb2[k * 64 + n];                   dst = Bb2F; }
            else             { val = Bb2[n * 64 + k];                   dst = Bb2TF; }
            dst[o] = f2h(val);
        }
    } else {
        const int e = (b - 6145) * 256 + threadIdx.x;    // 0..131071
        float val = 0.f;
        if (e < 98304) {
            const int net = e / 49152;
            const int o = e - net * 49152;
            const float* W1s = net ? Dw1 : Hw1;
            const float* W2s = net ? Dw2 : Hw2;
            if (o < 8192) {                 // W1f
                int ks = o & 31, n = (o >> 5) & 127, kt = o >> 12;
                val = W1s[(kt * 32 + ks) * 128 + n];
            } else if (o < 24576) {         // W2f
                int o2 = o - 8192;
                int ks = o2 & 31, n = (o2 >> 5) & 127, kt = o2 >> 12;
                val = W2s[(kt * 32 + ks) * 128 + n];
            } else if (o < 40960) {         // W2Tf
                int o3 = o - 24576;
                int ks = o3 & 31, n = (o3 >> 5) & 127, kt = o3 >> 12;
                val = W2s[n * 128 + kt * 32 + ks];
            } else {                        // W1Tf
                int o4 = o - 40960;
                int ks = o4 & 31, n = (o4 >> 5) & 63, kt = o4 >> 11;
                val = W1s[n * 128 + kt * 32 + ks];
            }
        } else if (e < 106496) {            // UW1f
            int o = e - 98304;
            int ks = o & 31, n = (o >> 5) & 127, kt = o >> 12;
            val = uw1[(kt * 32 + ks) * 128 + n];
        } else if (e < 114688) {            // UW2f
            int o = e - 106496;
            int ks = o & 31, n = (o >> 5) & 63, kt = o >> 11;
            val = uw2[(kt * 32 + ks) * 64 + n];
        } else if (e < 122880) {            // JW1f
            int o = e - 114688;
            int ks = o & 31, n = (o >> 5) & 127, kt = o >> 12;
            val = Jw1[(kt * 32 + ks) * 128 + n];
        } else {                            // BW1f
            int o = e - 122880;
            int ks = o & 31, n = (o >> 5) & 127, kt = o >> 12;
            val = Bw1[(kt * 32 + ks) * 128 + n];
        }
        SWF[e] = f2bf(val);
    }
}

// ================= K1: scalar nets + u-net via MFMA (32 rows/block, proven) =================
__device__ __forceinline__ void scalar_net(
    int tid, int r0,
    const ushort_t* zbp, ushort_t* S1, ushort_t* S2, ushort_t* S3,
    float* yacc, float* srow, float* Hrow,
    const ushort_t* W1f, const ushort_t* W2f, const ushort_t* W2Tf, const ushort_t* W1Tf,
    const float* B1, const float* B2, const float* W3, const float* B3,
    ushort_t* gOut, int storeH)
{
    const int lane = tid & 63, w = tid >> 6;
    const int mt = w & 1, nh = w >> 1;         // 2 row tiles x 4 col quarters
    const int cl = lane & 15, qq = lane >> 4;
    const int arow = mt * 16 + cl;
    const int crow = mt * 16 + qq * 4;

    // ---- L1 ----
    {
        short8 a0 = *(const short8*)&zbp[arow * 72 + (qq << 3)];
        short8 a1 = *(const short8*)&zbp[arow * 72 + 32 + (qq << 3)];
        #pragma unroll
        for (int nt = 0; nt < 2; ++nt) {
            int n = nh * 32 + nt * 16 + cl;
            f32x4 acc = {0.f, 0.f, 0.f, 0.f};
            short8 b0 = *(const short8*)&W1f[(n << 5) + (qq << 3)];
            short8 b1 = *(const short8*)&W1f[((128 + n) << 5) + (qq << 3)];
            acc = MFMA(a0, b0, acc); acc = MFMA(a1, b1, acc);
            float bv = B1[n];
            #pragma unroll
            for (int q = 0; q < 4; ++q) {
                float aa = acc[q] + bv;
                S1[(crow + q) * 136 + n] = f2bf(siluf(aa));
                S2[(crow + q) * 136 + n] = f2bf(silup(aa));
            }
        }
    }
    __syncthreads();
    // ---- L2 + y partial ----
    {
        short8 a[4];
        #pragma unroll
        for (int kt = 0; kt < 4; ++kt)
            a[kt] = *(const short8*)&S1[arow * 136 + kt * 32 + (qq << 3)];
        float yp[4] = {0.f, 0.f, 0.f, 0.f};
        #pragma unroll
        for (int nt = 0; nt < 2; ++nt) {
            int n = nh * 32 + nt * 16 + cl;
            f32x4 acc = {0.f, 0.f, 0.f, 0.f};
            #pragma unroll
            for (int kt = 0; kt < 4; ++kt) {
                short8 bb = *(const short8*)&W2f[((kt * 128 + n) << 5) + (qq << 3)];
                acc = MFMA(a[kt], bb, acc);
            }
            float bv = B2[n], w3v = W3[n];
            #pragma unroll
            for (int q = 0; q < 4; ++q) {
                float a2 = acc[q] + bv;
                yp[q] += siluf(a2) * w3v;
                S3[(crow + q) * 136 + n] = f2bf(w3v * silup(a2));
            }
        }
        #pragma unroll
        for (int q = 0; q < 4; ++q) {
            float p = yp[q];
            p += __shfl_xor(p, 1); p += __shfl_xor(p, 2);
            p += __shfl_xor(p, 4); p += __shfl_xor(p, 8);
            if (cl == 0) atomicAdd(&yacc[crow + q], p);
        }
    }
    __syncthreads();
    if (tid < 32) {
        float a3 = yacc[tid] + B3[0];
        srow[tid] = sigm(a3);
        if (storeH) Hrow[tid] = softplusf(a3);
        yacc[tid] = 0.f;
    }
    __syncthreads();
    // ---- bwd1 ----
    {
        short8 a[4];
        #pragma unroll
        for (int kt = 0; kt < 4; ++kt)
            a[kt] = *(const short8*)&S3[arow * 136 + kt * 32 + (qq << 3)];
        #pragma unroll
        for (int nt = 0; nt < 2; ++nt) {
            int n = nh * 32 + nt * 16 + cl;
            f32x4 acc = {0.f, 0.f, 0.f, 0.f};
            #pragma unroll
            for (int kt = 0; kt < 4; ++kt) {
                short8 bb = *(const short8*)&W2Tf[((kt * 128 + n) << 5) + (qq << 3)];
                acc = MFMA(a[kt], bb, acc);
            }
            #pragma unroll
            for (int q = 0; q < 4; ++q) {
                float sp;
                { union { unsigned int u; float f; } v;
                  v.u = ((unsigned int)S2[(crow + q) * 136 + n]) << 16; sp = v.f; }
                S1[(crow + q) * 136 + n] = f2bf(acc[q] * sp);
            }
        }
    }
    __syncthreads();
    // ---- bwd2: g -> global fp16 ----
    {
        short8 a[4];
        #pragma unroll
        for (int kt = 0; kt < 4; ++kt)
            a[kt] = *(const short8*)&S1[arow * 136 + kt * 32 + (qq << 3)];
        int n = nh * 16 + cl;
        f32x4 acc = {0.f, 0.f, 0.f, 0.f};
        #pragma unroll
        for (int kt = 0; kt < 4; ++kt) {
            short8 bb = *(const short8*)&W1Tf[((kt * 64 + n) << 5) + (qq << 3)];
            acc = MFMA(a[kt], bb, acc);
        }
        #pragma unroll
        for (int q = 0; q < 4; ++q) {
            int row = crow + q;
            gOut[(size_t)(r0 + row) * 64 + n] = f2h(srow[row] * acc[q]);
        }
    }
    __syncthreads();
}

extern "C" __global__ __launch_bounds__(512, 4)
void k1_kernel(const float* __restrict__ z,
               const float* __restrict__ Hb1, const float* __restrict__ Hb2,
               const float* __restrict__ Hw3, const float* __restrict__ Hb3,
               const float* __restrict__ Db1, const float* __restrict__ Db2,
               const float* __restrict__ Dw3, const float* __restrict__ Db3,
               const float* __restrict__ ub1, const float* __restrict__ ub2,
               const float* __restrict__ dtl, const float* __restrict__ etg,
               const ushort_t* __restrict__ SWF,
               ushort_t* __restrict__ gHbf, ushort_t* __restrict__ gDbf,
               float* __restrict__ out)
{
    __shared__ __align__(16) ushort_t zb[32][72];
    __shared__ __align__(16) ushort_t S1[32][136];
    __shared__ __align__(16) ushort_t S2[32][136];
    __shared__ __align__(16) ushort_t S3[32][136];
    __shared__ float yacc[32];
    __shared__ float srow[32];
    __shared__ float Hrow[32];

    const int tid = threadIdx.x;
    const int r0 = blockIdx.x * 32;

    {
        const float4* zg = (const float4*)(z + (size_t)r0 * 64);
        float4 v = zg[tid];
        int row = tid >> 4, c4 = (tid & 15) * 4;
        zb[row][c4 + 0] = f2bf(v.x); zb[row][c4 + 1] = f2bf(v.y);
        zb[row][c4 + 2] = f2bf(v.z); zb[row][c4 + 3] = f2bf(v.w);
        if (tid < 32) yacc[tid] = 0.f;
    }
    __syncthreads();

    scalar_net(tid, r0, &zb[0][0], &S1[0][0], &S2[0][0], &S3[0][0], yacc, srow, Hrow,
               SWF + OFF_HW1F, SWF + OFF_HW2F, SWF + OFF_HW2TF, SWF + OFF_HW1TF,
               Hb1, Hb2, Hw3, Hb3, gHbf, 1);
    scalar_net(tid, r0, &zb[0][0], &S1[0][0], &S2[0][0], &S3[0][0], yacc, srow, Hrow,
               SWF + OFF_DW1F, SWF + OFF_DW2F, SWF + OFF_DW2TF, SWF + OFF_DW1TF,
               Db1, Db2, Dw3, Db3, gDbf, 0);

    const int lane = tid & 63, w = tid >> 6;
    const int mt = w & 1, nh = w >> 1;
    const int cl = lane & 15, qq = lane >> 4;
    const int arow = mt * 16 + cl;
    const int crow = mt * 16 + qq * 4;

    // ---- u L1 (tanh) -> S1 ----
    {
        short8 a0 = *(const short8*)&zb[arow][(qq << 3)];
        short8 a1 = *(const short8*)&zb[arow][32 + (qq << 3)];
        const ushort_t* W1f = SWF + OFF_UW1F;
        #pragma unroll
        for (int nt = 0; nt < 2; ++nt) {
            int n = nh * 32 + nt * 16 + cl;
            f32x4 acc = {0.f, 0.f, 0.f, 0.f};
            short8 b0 = *(const short8*)&W1f[(n << 5) + (qq << 3)];
            short8 b1 = *(const short8*)&W1f[((128 + n) << 5) + (qq << 3)];
            acc = MFMA(a0, b0, acc); acc = MFMA(a1, b1, acc);
            float bv = ub1[n];
            #pragma unroll
            for (int q = 0; q < 4; ++q)
                S1[crow + q][n] = f2bf(tanhf(acc[q] + bv));
        }
    }
    __syncthreads();
    // ---- u L2 + base write ----
    {
        short8 a[4];
        #pragma unroll
        for (int kt = 0; kt < 4; ++kt)
            a[kt] = *(const short8*)&S1[arow][kt * 32 + (qq << 3)];
        const ushort_t* W2f = SWF + OFF_UW2F;
        const float dtv = 0.1f * sigm(dtl[0]);
        const float et = etg[0];
        int n = nh * 16 + cl;
        f32x4 acc = {0.f, 0.f, 0.f, 0.f};
        #pragma unroll
        for (int kt = 0; kt < 4; ++kt) {
            short8 bb = *(const short8*)&W2f[((kt * 64 + n) << 5) + (qq << 3)];
            acc = MFMA(a[kt], bb, acc);
        }
        float bv = ub2[n];
        #pragma unroll
        for (int q = 0; q < 4; ++q) {
            int row = crow + q;
            size_t idx = (size_t)(r0 + row) * 64 + n;
            out[idx] = z[idx] + dtv * 0.1f * (et - Hrow[row]) * (acc[q] + bv);
        }
    }
}

// ================= K2: heavy contractions, fp16, L2-direct (no weight staging) =================
// 32 rows/block, 256 threads = 4 waves: ch = col-half, ks = j parity; dual-row per wave.
#define LOADHF2H(SRC, HA, HB)                                                     \
    do {                                                                          \
        _Pragma("unroll")                                                         \
        for (int q4 = 0; q4 < 4; ++q4) {                                          \
            short8 sa = *(const short8*)&(SRC)[rr0][q4 * 32 + (qq << 3)];         \
            short8 sb = *(const short8*)&(SRC)[rr1][q4 * 32 + (qq << 3)];         \
            _Pragma("unroll")                                                     \
            for (int e = 0; e < 4; ++e) {                                         \
                h16x2 ta, tb;                                                     \
                ta[0] = u2h((ushort_t)sa[e * 2]); ta[1] = u2h((ushort_t)sa[e * 2 + 1]); \
                tb[0] = u2h((ushort_t)sb[e * 2]); tb[1] = u2h((ushort_t)sb[e * 2 + 1]); \
                (HA)[q4 * 4 + e] = ta;                                            \
                (HB)[q4 * 4 + e] = tb;                                            \
            }                                                                     \
        }                                                                         \
    } while (0)

// L2-direct heavy pass: per wave, 32 j's (parity ks), 8 b-loads + 16 MFMA per j, no barriers.
#define HEAVY_PASS(Wbase, BFbase, G, HA, HB, A00, A01, A10, A11)                  \
    do {                                                                          \
        _Pragma("unroll 2")                                                       \
        for (int jj = 0; jj < 32; ++jj) {                                         \
            const int j = 2 * jj + ks;                                            \
            const ushort_t* bp = (Wbase) + (size_t)j * 8192 + (qq << 9);          \
            h16x8 bf0[4], bf1[4];                                                 \
            _Pragma("unroll")                                                     \
            for (int ki = 0; ki < 4; ++ki) {                                      \
                bf0[ki] = *(const h16x8*)&bp[ki * 2048 + col0 * 8];               \
                bf1[ki] = *(const h16x8*)&bp[ki * 2048 + col1 * 8];               \
            }                                                                     \
            _Float16 gA = u2h((G)[rr0][j]);                                       \
            _Float16 gB = u2h((G)[rr1][j]);                                       \
            h16x2 gA2; gA2[0] = gA; gA2[1] = gA;                                  \
            h16x2 gB2; gB2[0] = gB; gB2[1] = gB;                                  \
            _Pragma("unroll")                                                     \
            for (int ki = 0; ki < 4; ++ki) {                                      \
                union { h16x2 h2[4]; h16x8 v; } aA, aB;                           \
                _Pragma("unroll")                                                 \
                for (int e = 0; e < 4; ++e) {                                     \
                    aA.h2[e] = (HA)[ki * 4 + e] * gA2;                            \
                    aB.h2[e] = (HB)[ki * 4 + e] * gB2;                            \
                }                                                                 \
                A00 = MFMAH(aA.v, bf0[ki], A00); A01 = MFMAH(aA.v, bf1[ki], A01); \
                A10 = MFMAH(aB.v, bf0[ki], A10); A11 = MFMAH(aB.v, bf1[ki], A11); \
            }                                                                     \
        }                                                                         \
        /* bias: kb = ks, each applied exactly once per ch */                     \
        {                                                                         \
            h16x8 abA = *(const h16x8*)&(G)[rr0][(ks << 5) + (qq << 3)];          \
            h16x8 abB = *(const h16x8*)&(G)[rr1][(ks << 5) + (qq << 3)];          \
            const ushort_t* bpb = (BFbase) + (ks << 11) + (qq << 9);              \
            h16x8 b0 = *(const h16x8*)&bpb[col0 * 8];                             \
            h16x8 b1 = *(const h16x8*)&bpb[col1 * 8];                             \
            A00 = MFMAH(abA, b0, A00); A01 = MFMAH(abA, b1, A01);                 \
            A10 = MFMAH(abB, b0, A10); A11 = MFMAH(abB, b1, A11);                 \
        }                                                                         \
        /* combine ks=1 partials into ks=0 */                                     \
        __syncthreads();                                                          \
        if (ks == 1) {                                                            \
            _Pragma("unroll")                                                     \
            for (int q = 0; q < 4; ++q) {                                         \
                Pb[orow0 + q][col0] = A00[q]; Pb[orow0 + q][col1] = A01[q];       \
                Pb[orow1 + q][col0] = A10[q]; Pb[orow1 + q][col1] = A11[q];       \
            }                                                                     \
        }                                                                         \
        __syncthreads();                                                          \
        if (ks == 0) {                                                            \
            _Pragma("unroll")                                                     \
            for (int q = 0; q < 4; ++q) {                                         \
                A00[q] += Pb[orow0 + q][col0]; A01[q] += Pb[orow0 + q][col1];     \
                A10[q] += Pb[orow1 + q][col0]; A11[q] += Pb[orow1 + q][col1];     \
            }                                                                     \
        }                                                                         \
        __syncthreads();                                                          \
    } while (0)

extern "C" __global__ __launch_bounds__(256, 3)
void k2_kernel(const float* __restrict__ z,
               const float* __restrict__ Jb1, const float* __restrict__ Bb1,
               const float* __restrict__ dtl,
               const ushort_t* __restrict__ JW, const ushort_t* __restrict__ BW1,
               const ushort_t* __restrict__ BW2,
               const ushort_t* __restrict__ JbdF, const ushort_t* __restrict__ Bb2F,
               const ushort_t* __restrict__ Bb2TF,
               const ushort_t* __restrict__ SWF,
               const ushort_t* __restrict__ gHbf, const ushort_t* __restrict__ gDbf,
               float* __restrict__ out)
{
    __shared__ __align__(16) ushort_t zb[32][72];
    __shared__ __align__(16) ushort_t hJ2[32][136];   // fp16
    __shared__ __align__(16) ushort_t hB2[32][136];   // fp16
    __shared__ __align__(16) ushort_t gHb[32][72];    // fp16
    __shared__ __align__(16) ushort_t gDb[32][72];    // fp16
    __shared__ __align__(16) ushort_t vb2[32][72];    // fp16
    __shared__ __align__(16) float Pb[32][68];        // f32 partial combine

    const int tid = threadIdx.x;
    const int r0 = blockIdx.x * 32;

    // stage z (bf16), gH, gD (fp16)
    {
        const float4* zg = (const float4*)(z + (size_t)r0 * 64);
        #pragma unroll
        for (int it = 0; it < 2; ++it) {
            int i = it * 256 + tid;
            float4 v = zg[i];
            int row = i >> 4, c4 = (i & 15) * 4;
            zb[row][c4 + 0] = f2bf(v.x); zb[row][c4 + 1] = f2bf(v.y);
            zb[row][c4 + 2] = f2bf(v.z); zb[row][c4 + 3] = f2bf(v.w);
        }
        const short8* gh = (const short8*)(gHbf + (size_t)r0 * 64);
        const short8* gd = (const short8*)(gDbf + (size_t)r0 * 64);
        int row = tid >> 3, s = tid & 7;
        *(short8*)&gHb[row][s * 8] = gh[tid];
        *(short8*)&gDb[row][s * 8] = gd[tid];
    }
    __syncthreads();

    const int lane = tid & 63, w = tid >> 6;   // w in 0..3
    const int cl = lane & 15, qq = lane >> 4;
    const int mt = w & 1, nh = w >> 1;         // L1 mapping: 2 row-tiles x 2 col-halves
    const int arow = mt * 16 + cl;
    const int crowL = mt * 16 + qq * 4;

    // ---- J/B layer-1 via bf16 MFMA, outputs fp16 ----
    {
        short8 a0 = *(const short8*)&zb[arow][(qq << 3)];
        short8 a1 = *(const short8*)&zb[arow][32 + (qq << 3)];
        const ushort_t* JW1f = SWF + OFF_JW1F;
        const ushort_t* BW1f = SWF + OFF_BW1F;
        #pragma unroll
        for (int nt = 0; nt < 4; ++nt) {
            int n = nh * 64 + nt * 16 + cl;
            f32x4 accJ = {0.f, 0.f, 0.f, 0.f}, accB = {0.f, 0.f, 0.f, 0.f};
            short8 jb0 = *(const short8*)&JW1f[(n << 5) + (qq << 3)];
            short8 jb1 = *(const short8*)&JW1f[((128 + n) << 5) + (qq << 3)];
            accJ = MFMA(a0, jb0, accJ); accJ = MFMA(a1, jb1, accJ);
            short8 bb0 = *(const short8*)&BW1f[(n << 5) + (qq << 3)];
            short8 bb1 = *(const short8*)&BW1f[((128 + n) << 5) + (qq << 3)];
            accB = MFMA(a0, bb0, accB); accB = MFMA(a1, bb1, accB);
            float jbv = Jb1[n], bbv = Bb1[n];
            #pragma unroll
            for (int q = 0; q < 4; ++q) {
                hJ2[crowL + q][n] = f2h(siluf(accJ[q] + jbv));
                hB2[crowL + q][n] = f2h(siluf(accB[q] + bbv));
            }
        }
    }
    __syncthreads();

    // heavy mapping: 2 col-halves x 2 j-parities; both row-tiles per wave
    const int ch = w & 1;               // col half
    const int ks = w >> 1;              // j parity
    const int rr0 = cl;
    const int rr1 = cl + 16;
    const int col0 = ch * 32 + cl;
    const int col1 = col0 + 16;
    const int orow0 = qq * 4;
    const int orow1 = orow0 + 16;

    h16x2 hfJA[16], hfJB[16], hfBA[16], hfBB[16];
    f32x4 c00 = {0,0,0,0}, c01 = {0,0,0,0}, c10 = {0,0,0,0}, c11 = {0,0,0,0};
    f32x4 v00 = {0,0,0,0}, v01 = {0,0,0,0}, v10 = {0,0,0,0}, v11 = {0,0,0,0};
    f32x4 d00 = {0,0,0,0}, d01 = {0,0,0,0}, d10 = {0,0,0,0}, d11 = {0,0,0,0};

    // ---- pass 1: cons = (A - A^T) gH ----
    LOADHF2H(hJ2, hfJA, hfJB);
    HEAVY_PASS(JW, JbdF, gHb, hfJA, hfJB, c00, c01, c10, c11);

    // ---- pass 2: v = Bm^T gD ----
    LOADHF2H(hB2, hfBA, hfBB);
    HEAVY_PASS(BW1, Bb2F, gDb, hfBA, hfBB, v00, v01, v10, v11);

    // ks=0 holds full v -> write vb2 (fp16)
    if (ks == 0) {
        #pragma unroll
        for (int q = 0; q < 4; ++q) {
            vb2[orow0 + q][col0] = f2h(v00[q]); vb2[orow0 + q][col1] = f2h(v01[q]);
            vb2[orow1 + q][col0] = f2h(v10[q]); vb2[orow1 + q][col1] = f2h(v11[q]);
        }
    }
    __syncthreads();

    // ---- pass 3: diss = Bm v ----
    HEAVY_PASS(BW2, Bb2TF, vb2, hfBA, hfBB, d00, d01, d10, d11);

    // ---- epilogue (ks=0 holds full sums) ----
    if (ks == 0) {
        const float dtv = 0.1f * sigm(dtl[0]);
        #pragma unroll
        for (int q = 0; q < 4; ++q) {
            size_t i00 = (size_t)(r0 + orow0 + q) * 64 + col0;
            size_t i01 = (size_t)(r0 + orow0 + q) * 64 + col1;
            size_t i10 = (size_t)(r0 + orow1 + q) * 64 + col0;
            size_t i11 = (size_t)(r0 + orow1 + q) * 64 + col1;
            out[i00] += dtv * (c00[q] - d00[q]);
            out[i01] += dtv * (c01[q] - d01[q]);
            out[i10] += dtv * (c10[q] - d10[q]);
            out[i11] += dtv * (c11[q] - d11[q]);
        }
    }
}

extern "C" void kernel_launch(void* const* d_in, const int* in_sizes, int n_in,
                              void* d_out, int out_size, void* d_ws, size_t ws_size,
                              hipStream_t stream) {
    const float* p[27];
    for (int i = 0; i < 27; ++i) p[i] = (const float*)d_in[i];
    ushort_t* JW    = (ushort_t*)d_ws;
    ushort_t* BW1   = JW + 524288;
    ushort_t* BW2   = BW1 + 524288;
    ushort_t* JbdF  = BW2 + 524288;
    ushort_t* Bb2F  = JbdF + 4096;
    ushort_t* Bb2TF = Bb2F + 4096;
    ushort_t* gHbf  = Bb2TF + 4096;
    ushort_t* gDbf  = gHbf + (size_t)16384 * 64;
    ushort_t* SWF   = gDbf + (size_t)16384 * 64;

    hipLaunchKernelGGL(prep3_kernel, dim3(6657), dim3(256), 0, stream,
                       p[15], p[16], p[19], p[20],
                       p[1], p[3], p[7], p[9],
                       p[21], p[23], p[13], p[17],
                       JW, BW1, BW2, JbdF, Bb2F, Bb2TF, SWF);

    const int batch = in_sizes[0] / DIM;
    hipLaunchKernelGGL(k1_kernel, dim3(batch / 32), dim3(512), 0, stream,
                       p[0],
                       p[2], p[4], p[5], p[6],
                       p[8], p[10], p[11], p[12],
                       p[22], p[24],
                       p[25], p[26],
                       SWF, gHbf, gDbf, (float*)d_out);

    hipLaunchKernelGGL(k2_kernel, dim3(batch / 32), dim3(256), 0, stream,
                       p[0], p[14], p[18], p[25],
                       JW, BW1, BW2, JbdF, Bb2F, Bb2TF, SWF,
                       gHbf, gDbf, (float*)d_out);
}